// Round 1
// baseline (1665.344 us; speedup 1.0000x reference)
//
#include <hip/hip_runtime.h>

// SAGE layer, restructured: because the message Linear is applied before a
// linear segment-mean, we can aggregate RAW [nf[src]||ef] features per dst
// node first (scatter-add), then apply W_msg once per node:
//   h_neigh[n] = deg>0 ? (agg[n]/deg[n]) @ W_msg^T + b_msg : 0
// This turns 13.1 GFLOP of per-edge GEMM into 0.8 GFLOP of per-node GEMM and
// makes the kernel memory-bound on the edge traversal.

__global__ void transpose_w(const float* __restrict__ Wm, const float* __restrict__ Wa,
                            float* __restrict__ WmT, float* __restrict__ WaT) {
    int idx = blockIdx.x * blockDim.x + threadIdx.x;   // 0..16383
    if (idx >= 2 * 64 * 128) return;
    const float* S = (idx < 8192) ? Wm : Wa;
    float*       T = (idx < 8192) ? WmT : WaT;
    int r = idx & 8191;
    int o = r >> 7;     // 0..63  (output channel)
    int f = r & 127;    // 0..127 (input feature)
    T[f * 64 + o] = S[o * 128 + f];                    // [f][o] layout: coalesced in node kernel
}

// One edge handled by 32 consecutive threads, each moving a float4.
// Lanes 0..15: gather nfeats[src[e]] (row-contiguous 256B), lanes 16..31:
// coalesced efeats[e]. Scatter-add into agg[dst[e]][0:128].
__global__ void edge_scatter(const float4* __restrict__ nf4, const float4* __restrict__ ef4,
                             const int* __restrict__ src, const int* __restrict__ dst,
                             float* __restrict__ agg, float* __restrict__ deg, int E) {
    int idx = blockIdx.x * blockDim.x + threadIdx.x;
    int e = idx >> 5;
    int q = idx & 31;
    if (e >= E) return;
    int d = dst[e];
    float4 v;
    if (q < 16) {
        int s = src[e];
        v = nf4[(size_t)s * 16 + q];
        if (q == 0) atomicAdd(&deg[d], 1.0f);
    } else {
        v = ef4[(size_t)e * 16 + (q - 16)];
    }
    float* base = &agg[(size_t)d * 128 + q * 4];
    atomicAdd(base + 0, v.x);
    atomicAdd(base + 1, v.y);
    atomicAdd(base + 2, v.z);
    atomicAdd(base + 3, v.w);
}

// One wave (64 threads) per block, 4 nodes per block. Thread t computes
// output channel o=t for all 4 nodes (weight load reused 4x). x rows staged
// in LDS, read as broadcast; weights in [f][o] layout -> coalesced loads.
__global__ __launch_bounds__(64) void node_update(
    const float* __restrict__ nfeats, const float* __restrict__ agg,
    const float* __restrict__ deg,    const float* __restrict__ WmT,
    const float* __restrict__ bm,     const float* __restrict__ WaT,
    const float* __restrict__ ba,     float* __restrict__ out, int N) {
    __shared__ float s_x[4][128];   // [nf_sum || ef_sum] / deg
    __shared__ float s_z[4][128];   // [nfeats || h_neigh]
    int t = threadIdx.x;            // 0..63
    int base = blockIdx.x * 4;
    float dgs[4];
    #pragma unroll
    for (int j = 0; j < 4; ++j) {
        int n = base + j;
        if (n >= N) { dgs[j] = 0.f; continue; }
        float dg = deg[n];
        dgs[j] = dg;
        float inv = dg > 0.f ? 1.0f / dg : 0.0f;
        s_x[j][t]      = agg[(size_t)n * 128 + t] * inv;
        s_x[j][64 + t] = agg[(size_t)n * 128 + 64 + t] * inv;
        s_z[j][t]      = nfeats[(size_t)n * 64 + t];
    }
    __syncthreads();

    int o = t;
    float acc[4] = {0.f, 0.f, 0.f, 0.f};
    for (int f = 0; f < 128; f += 2) {
        float w0 = WmT[(f    ) * 64 + o];
        float w1 = WmT[(f + 1) * 64 + o];
        #pragma unroll
        for (int j = 0; j < 4; ++j)
            acc[j] += s_x[j][f] * w0 + s_x[j][f + 1] * w1;
    }
    float bmo = bm[o];
    #pragma unroll
    for (int j = 0; j < 4; ++j) {
        float hn = dgs[j] > 0.f ? acc[j] + bmo : 0.f;   // isolated nodes -> 0
        s_z[j][64 + o] = hn;
    }
    __syncthreads();

    float acc2[4] = {0.f, 0.f, 0.f, 0.f};
    for (int f = 0; f < 128; f += 2) {
        float w0 = WaT[(f    ) * 64 + o];
        float w1 = WaT[(f + 1) * 64 + o];
        #pragma unroll
        for (int j = 0; j < 4; ++j)
            acc2[j] += s_z[j][f] * w0 + s_z[j][f + 1] * w1;
    }
    float bao = ba[o];
    #pragma unroll
    for (int j = 0; j < 4; ++j) {
        int n = base + j;
        if (n < N) {
            float h = acc2[j] + bao;
            out[(size_t)n * 64 + o] = h > 0.f ? h : 0.f;
        }
    }
}

extern "C" void kernel_launch(void* const* d_in, const int* in_sizes, int n_in,
                              void* d_out, int out_size, void* d_ws, size_t ws_size,
                              hipStream_t stream) {
    const float* nfeats = (const float*)d_in[0];   // [N,1,64]
    const float* efeats = (const float*)d_in[1];   // [E,1,64]
    const int*   src    = (const int*)d_in[2];     // [E]
    const int*   dst    = (const int*)d_in[3];     // [E]
    const float* Wm     = (const float*)d_in[4];   // [64,128]
    const float* bm     = (const float*)d_in[5];   // [64]
    const float* Wa     = (const float*)d_in[6];   // [64,128]
    const float* ba     = (const float*)d_in[7];   // [64]
    float* out = (float*)d_out;                    // [N,1,64] fp32

    const int N = in_sizes[0] / 64;
    const int E = in_sizes[2];

    // workspace layout (floats): agg[N*128] | deg[N] | WmT[8192] | WaT[8192]
    float* agg = (float*)d_ws;
    float* deg = agg + (size_t)N * 128;
    float* WmT = deg + N;
    float* WaT = WmT + 8192;

    // zero the accumulators (ws is poisoned 0xAA before every call)
    hipMemsetAsync(d_ws, 0, (size_t)N * 129 * sizeof(float), stream);

    transpose_w<<<64, 256, 0, stream>>>(Wm, Wa, WmT, WaT);

    int ethreads = E * 32;                         // 32 threads per edge
    edge_scatter<<<(ethreads + 255) / 256, 256, 0, stream>>>(
        (const float4*)nfeats, (const float4*)efeats, src, dst, agg, deg, E);

    node_update<<<(N + 3) / 4, 64, 0, stream>>>(
        nfeats, agg, deg, WmT, bm, WaT, ba, out, N);
}

// Round 2
// 583.813 us; speedup vs baseline: 2.8525x; 2.8525x over previous
//
#include <hip/hip_runtime.h>

// SAGE layer. Key restructurings:
// 1. Message linear commutes with segment-mean -> aggregate RAW [nf[src]||ef]
//    per dst node, apply W_msg once per node (13.1 GFLOP -> 0.8 GFLOP).
// 2. Round 1 showed the f32 atomic scatter writes 1.66 GB through to HBM
//    (102M atomics). Replace with on-device CSR-by-dst build (1.6M int
//    atomics) + one wave per node doing register accumulation, zero atomics.

#define NWAVE 64

__global__ void transpose_w(const float* __restrict__ Wm, const float* __restrict__ Wa,
                            float* __restrict__ WmT, float* __restrict__ WaT) {
    int idx = blockIdx.x * blockDim.x + threadIdx.x;   // 0..16383
    if (idx >= 2 * 64 * 128) return;
    const float* S = (idx < 8192) ? Wm : Wa;
    float*       T = (idx < 8192) ? WmT : WaT;
    int r = idx & 8191;
    int o = r >> 7;     // 0..63  (output channel)
    int f = r & 127;    // 0..127 (input feature)
    T[f * 64 + o] = S[o * 128 + f];                    // [f][o]: coalesced in node kernel
}

// --- CSR build ---------------------------------------------------------------

__global__ void histogram(const int* __restrict__ dst, int* __restrict__ cnt, int E) {
    int e = blockIdx.x * blockDim.x + threadIdx.x;
    if (e >= E) return;
    atomicAdd(&cnt[dst[e]], 1);
}

// Single-block exclusive scan over cnt[0..N) -> offs (and a second copy in
// cursor for the scatter's atomic placement). 1024 threads, chunked
// Hillis-Steele in LDS with running carry.
__global__ __launch_bounds__(1024) void scan_offsets(
    const int* __restrict__ cnt, int* __restrict__ offs, int* __restrict__ cursor, int N) {
    __shared__ int s[1024];
    __shared__ int s_carry;
    int t = threadIdx.x;
    if (t == 0) s_carry = 0;
    __syncthreads();
    for (int base = 0; base < N; base += 1024) {
        int i = base + t;
        int v = (i < N) ? cnt[i] : 0;
        s[t] = v;
        __syncthreads();
        #pragma unroll
        for (int off = 1; off < 1024; off <<= 1) {
            int tmp = (t >= off) ? s[t - off] : 0;
            __syncthreads();
            s[t] += tmp;
            __syncthreads();
        }
        int carry = s_carry;                 // written before last chunk's end barrier
        if (i < N) {
            int excl = carry + s[t] - v;
            offs[i]   = excl;
            cursor[i] = excl;
        }
        __syncthreads();                     // all reads of s_carry done
        if (t == 1023) s_carry = carry + s[1023];
        __syncthreads();
    }
    if (t == 0) offs[N] = s_carry;           // == E
}

__global__ void scatter_eids(const int* __restrict__ dst, int* __restrict__ cursor,
                             int* __restrict__ eids, int E) {
    int e = blockIdx.x * blockDim.x + threadIdx.x;
    if (e >= E) return;
    int pos = atomicAdd(&cursor[dst[e]], 1);
    eids[pos] = e;
}

// --- Aggregation: one wave per node, no atomics ------------------------------
// Lane t accumulates feature t of nf-sum and feature t of ef-sum. Edge ids and
// src indices are prefetched one-per-lane and broadcast via __shfl so the
// inner loop is just two coalesced 256B row reads per edge.
__global__ __launch_bounds__(256) void gather_csr(
    const float* __restrict__ nfeats, const float* __restrict__ efeats,
    const int* __restrict__ src, const int* __restrict__ offs,
    const int* __restrict__ eids, float* __restrict__ agg,
    float* __restrict__ deg, int N) {
    int wave = threadIdx.x >> 6;
    int lane = threadIdx.x & 63;
    int n = blockIdx.x * 4 + wave;
    if (n >= N) return;
    int start = offs[n];
    int end   = offs[n + 1];
    float acc_nf = 0.f, acc_ef = 0.f;
    for (int base = start; base < end; base += 64) {
        int m = end - base; if (m > 64) m = 64;
        int eid_l = 0, src_l = 0;
        if (lane < m) {
            eid_l = eids[base + lane];
            src_l = src[eid_l];
        }
        for (int k = 0; k < m; ++k) {
            int eid = __shfl(eid_l, k);
            int s   = __shfl(src_l, k);
            acc_nf += nfeats[(size_t)s   * 64 + lane];
            acc_ef += efeats[(size_t)eid * 64 + lane];
        }
    }
    agg[(size_t)n * 128 + lane]      = acc_nf;
    agg[(size_t)n * 128 + 64 + lane] = acc_ef;
    if (lane == 0) deg[n] = (float)(end - start);
}

// --- Node update (unchanged from round 1, verified correct) ------------------
__global__ __launch_bounds__(64) void node_update(
    const float* __restrict__ nfeats, const float* __restrict__ agg,
    const float* __restrict__ deg,    const float* __restrict__ WmT,
    const float* __restrict__ bm,     const float* __restrict__ WaT,
    const float* __restrict__ ba,     float* __restrict__ out, int N) {
    __shared__ float s_x[4][128];   // [nf_sum || ef_sum] / deg
    __shared__ float s_z[4][128];   // [nfeats || h_neigh]
    int t = threadIdx.x;            // 0..63
    int base = blockIdx.x * 4;
    float dgs[4];
    #pragma unroll
    for (int j = 0; j < 4; ++j) {
        int n = base + j;
        if (n >= N) { dgs[j] = 0.f; continue; }
        float dg = deg[n];
        dgs[j] = dg;
        float inv = dg > 0.f ? 1.0f / dg : 0.0f;
        s_x[j][t]      = agg[(size_t)n * 128 + t] * inv;
        s_x[j][64 + t] = agg[(size_t)n * 128 + 64 + t] * inv;
        s_z[j][t]      = nfeats[(size_t)n * 64 + t];
    }
    __syncthreads();

    int o = t;
    float acc[4] = {0.f, 0.f, 0.f, 0.f};
    for (int f = 0; f < 128; f += 2) {
        float w0 = WmT[(f    ) * 64 + o];
        float w1 = WmT[(f + 1) * 64 + o];
        #pragma unroll
        for (int j = 0; j < 4; ++j)
            acc[j] += s_x[j][f] * w0 + s_x[j][f + 1] * w1;
    }
    float bmo = bm[o];
    #pragma unroll
    for (int j = 0; j < 4; ++j) {
        float hn = dgs[j] > 0.f ? acc[j] + bmo : 0.f;   // isolated nodes -> 0
        s_z[j][64 + o] = hn;
    }
    __syncthreads();

    float acc2[4] = {0.f, 0.f, 0.f, 0.f};
    for (int f = 0; f < 128; f += 2) {
        float w0 = WaT[(f    ) * 64 + o];
        float w1 = WaT[(f + 1) * 64 + o];
        #pragma unroll
        for (int j = 0; j < 4; ++j)
            acc2[j] += s_z[j][f] * w0 + s_z[j][f + 1] * w1;
    }
    float bao = ba[o];
    #pragma unroll
    for (int j = 0; j < 4; ++j) {
        int n = base + j;
        if (n < N) {
            float h = acc2[j] + bao;
            out[(size_t)n * 64 + o] = h > 0.f ? h : 0.f;
        }
    }
}

extern "C" void kernel_launch(void* const* d_in, const int* in_sizes, int n_in,
                              void* d_out, int out_size, void* d_ws, size_t ws_size,
                              hipStream_t stream) {
    const float* nfeats = (const float*)d_in[0];   // [N,1,64]
    const float* efeats = (const float*)d_in[1];   // [E,1,64]
    const int*   src    = (const int*)d_in[2];     // [E]
    const int*   dst    = (const int*)d_in[3];     // [E]
    const float* Wm     = (const float*)d_in[4];   // [64,128]
    const float* bm     = (const float*)d_in[5];   // [64]
    const float* Wa     = (const float*)d_in[6];   // [64,128]
    const float* ba     = (const float*)d_in[7];   // [64]
    float* out = (float*)d_out;                    // [N,1,64] fp32

    const int N = in_sizes[0] / 64;
    const int E = in_sizes[2];

    // workspace layout:
    float* agg    = (float*)d_ws;                  // N*128 f32
    float* deg    = agg + (size_t)N * 128;         // N f32
    float* WmT    = deg + N;                       // 8192 f32
    float* WaT    = WmT + 8192;                    // 8192 f32
    int*   cnt    = (int*)(WaT + 8192);            // N i32
    int*   offs   = cnt + N;                       // N+1 i32
    int*   cursor = offs + N + 1;                  // N i32
    int*   eids   = cursor + N;                    // E i32

    hipMemsetAsync(cnt, 0, (size_t)N * sizeof(int), stream);

    transpose_w<<<64, 256, 0, stream>>>(Wm, Wa, WmT, WaT);
    histogram<<<(E + 255) / 256, 256, 0, stream>>>(dst, cnt, E);
    scan_offsets<<<1, 1024, 0, stream>>>(cnt, offs, cursor, N);
    scatter_eids<<<(E + 255) / 256, 256, 0, stream>>>(dst, cursor, eids, E);
    gather_csr<<<(N + 3) / 4, 256, 0, stream>>>(nfeats, efeats, src, offs, eids, agg, deg, N);
    node_update<<<(N + 3) / 4, 64, 0, stream>>>(nfeats, agg, deg, WmT, bm, WaT, ba, out, N);
}

// Round 4
// 469.194 us; speedup vs baseline: 3.5494x; 1.2443x over previous
//
#include <hip/hip_runtime.h>

// SAGE layer. Structure:
// 1. Message linear commutes with segment-mean -> aggregate RAW [nf[src]||ef]
//    per dst node, apply W_msg once per node (13.1 GFLOP -> 0.8 GFLOP).
// 2. CSR-by-dst built on device (histogram -> hierarchical scan -> scatter),
//    then one wave per node accumulates in registers: zero f32 atomics.
// 3. gather_csr processes 4 edges concurrently per wave (16 lanes x float4
//    per row) for 1KB/instruction memory parallelism; src is pre-permuted
//    into CSR order so index reads are coalesced.

__global__ void transpose_w(const float* __restrict__ Wm, const float* __restrict__ Wa,
                            float* __restrict__ WmT, float* __restrict__ WaT) {
    int idx = blockIdx.x * blockDim.x + threadIdx.x;   // 0..16383
    if (idx >= 2 * 64 * 128) return;
    const float* S = (idx < 8192) ? Wm : Wa;
    float*       T = (idx < 8192) ? WmT : WaT;
    int r = idx & 8191;
    int o = r >> 7;     // output channel
    int f = r & 127;    // input feature
    T[f * 64 + o] = S[o * 128 + f];                    // [f][o]: coalesced in node kernel
}

// --- CSR build ---------------------------------------------------------------

__global__ void histogram(const int* __restrict__ dst, int* __restrict__ cnt, int E) {
    int e = blockIdx.x * blockDim.x + threadIdx.x;
    if (e >= E) return;
    atomicAdd(&cnt[dst[e]], 1);
}

// Hierarchical exclusive scan: local 256-chunk scan -> scan of block sums ->
// add-back. (Round 2's single-block scan ran on 1 CU and dominated runtime.)
__global__ __launch_bounds__(256) void scan_local(
    const int* __restrict__ cnt, int* __restrict__ excl, int* __restrict__ bsums, int N) {
    __shared__ int s[256];
    int t = threadIdx.x;
    int i = blockIdx.x * 256 + t;
    int v = (i < N) ? cnt[i] : 0;
    s[t] = v;
    __syncthreads();
    #pragma unroll
    for (int off = 1; off < 256; off <<= 1) {
        int tmp = (t >= off) ? s[t - off] : 0;
        __syncthreads();
        s[t] += tmp;
        __syncthreads();
    }
    if (i < N) excl[i] = s[t] - v;          // local exclusive
    if (t == 255) bsums[blockIdx.x] = s[255];
}

__global__ __launch_bounds__(256) void scan_bsums(int* __restrict__ bsums, int B) {
    __shared__ int s[256];
    int t = threadIdx.x;
    int v = (t < B) ? bsums[t] : 0;
    s[t] = v;
    __syncthreads();
    #pragma unroll
    for (int off = 1; off < 256; off <<= 1) {
        int tmp = (t >= off) ? s[t - off] : 0;
        __syncthreads();
        s[t] += tmp;
        __syncthreads();
    }
    if (t < B) bsums[t] = s[t] - v;         // exclusive block offsets
}

__global__ __launch_bounds__(256) void scan_add(
    int* __restrict__ offs, int* __restrict__ cursor,
    const int* __restrict__ bsums, int N, int E) {
    int i = blockIdx.x * 256 + threadIdx.x;
    if (i < N) {
        int v = offs[i] + bsums[blockIdx.x];
        offs[i]   = v;
        cursor[i] = v;
    }
    if (i == 0) offs[N] = E;
}

__global__ void scatter_eids(const int* __restrict__ dst, const int* __restrict__ src,
                             int* __restrict__ cursor, int* __restrict__ eids,
                             int* __restrict__ src_perm, int E) {
    int e = blockIdx.x * blockDim.x + threadIdx.x;
    if (e >= E) return;
    int pos = atomicAdd(&cursor[dst[e]], 1);
    eids[pos]     = e;
    src_perm[pos] = src[e];                 // src in CSR order -> coalesced in gather
}

// --- Aggregation: one wave per node, 4 edges in flight, no atomics -----------
__device__ inline float4 xor_add(float4 v, int m) {
    v.x += __shfl_xor(v.x, m);
    v.y += __shfl_xor(v.y, m);
    v.z += __shfl_xor(v.z, m);
    v.w += __shfl_xor(v.w, m);
    return v;
}

__global__ __launch_bounds__(256) void gather_csr(
    const float4* __restrict__ nf4, const float4* __restrict__ ef4,
    const int* __restrict__ src_perm, const int* __restrict__ offs,
    const int* __restrict__ eids, float4* __restrict__ agg4,
    float* __restrict__ deg, int N) {
    int wave = threadIdx.x >> 6;
    int lane = threadIdx.x & 63;
    int n = blockIdx.x * 4 + wave;
    if (n >= N) return;
    int g = lane >> 4;          // edge group 0..3
    int l = lane & 15;          // float4 slot within a 256B row
    int start = offs[n];
    int end   = offs[n + 1];
    float4 anf = {0.f, 0.f, 0.f, 0.f};
    float4 aef = {0.f, 0.f, 0.f, 0.f};
    for (int base = start; base < end; base += 64) {
        int m = end - base; if (m > 64) m = 64;
        int eid_l = 0, sp_l = 0;
        if (lane < m) {
            eid_l = eids[base + lane];
            sp_l  = src_perm[base + lane];
        }
        int jmax = (m + 3) >> 2;            // uniform trip count across wave
        for (int j = 0; j < jmax; ++j) {
            int k = (j << 2) + g;           // this group's edge slot
            int eid = __shfl(eid_l, k);
            int s   = __shfl(sp_l, k);
            if (k < m) {
                float4 a = nf4[(size_t)s   * 16 + l];
                float4 b = ef4[(size_t)eid * 16 + l];
                anf.x += a.x; anf.y += a.y; anf.z += a.z; anf.w += a.w;
                aef.x += b.x; aef.y += b.y; aef.z += b.z; aef.w += b.w;
            }
        }
    }
    // cross-group reduce: lanes {l, l+16, l+32, l+48} hold partials of slot l
    anf = xor_add(anf, 16); anf = xor_add(anf, 32);
    aef = xor_add(aef, 16); aef = xor_add(aef, 32);
    if (g == 0)      agg4[(size_t)n * 32 + l]      = anf;
    else if (g == 1) agg4[(size_t)n * 32 + 16 + l] = aef;
    if (lane == 0) deg[n] = (float)(end - start);
}

// --- Node update -------------------------------------------------------------
__global__ __launch_bounds__(64) void node_update(
    const float* __restrict__ nfeats, const float* __restrict__ agg,
    const float* __restrict__ deg,    const float* __restrict__ WmT,
    const float* __restrict__ bm,     const float* __restrict__ WaT,
    const float* __restrict__ ba,     float* __restrict__ out, int N) {
    __shared__ float s_x[4][128];   // [nf_sum || ef_sum] / deg
    __shared__ float s_z[4][128];   // [nfeats || h_neigh]
    int t = threadIdx.x;            // 0..63
    int base = blockIdx.x * 4;
    float dgs[4];
    #pragma unroll
    for (int j = 0; j < 4; ++j) {
        int n = base + j;
        if (n >= N) { dgs[j] = 0.f; continue; }
        float dg = deg[n];
        dgs[j] = dg;
        float inv = dg > 0.f ? 1.0f / dg : 0.0f;
        s_x[j][t]      = agg[(size_t)n * 128 + t] * inv;
        s_x[j][64 + t] = agg[(size_t)n * 128 + 64 + t] * inv;
        s_z[j][t]      = nfeats[(size_t)n * 64 + t];
    }
    __syncthreads();

    int o = t;
    float acc[4] = {0.f, 0.f, 0.f, 0.f};
    for (int f = 0; f < 128; f += 2) {
        float w0 = WmT[(f    ) * 64 + o];
        float w1 = WmT[(f + 1) * 64 + o];
        #pragma unroll
        for (int j = 0; j < 4; ++j)
            acc[j] += s_x[j][f] * w0 + s_x[j][f + 1] * w1;
    }
    float bmo = bm[o];
    #pragma unroll
    for (int j = 0; j < 4; ++j) {
        float hn = dgs[j] > 0.f ? acc[j] + bmo : 0.f;   // isolated nodes -> 0
        s_z[j][64 + o] = hn;
    }
    __syncthreads();

    float acc2[4] = {0.f, 0.f, 0.f, 0.f};
    for (int f = 0; f < 128; f += 2) {
        float w0 = WaT[(f    ) * 64 + o];
        float w1 = WaT[(f + 1) * 64 + o];
        #pragma unroll
        for (int j = 0; j < 4; ++j)
            acc2[j] += s_z[j][f] * w0 + s_z[j][f + 1] * w1;
    }
    float bao = ba[o];
    #pragma unroll
    for (int j = 0; j < 4; ++j) {
        int n = base + j;
        if (n < N) {
            float h = acc2[j] + bao;
            out[(size_t)n * 64 + o] = h > 0.f ? h : 0.f;
        }
    }
}

extern "C" void kernel_launch(void* const* d_in, const int* in_sizes, int n_in,
                              void* d_out, int out_size, void* d_ws, size_t ws_size,
                              hipStream_t stream) {
    const float* nfeats = (const float*)d_in[0];   // [N,1,64]
    const float* efeats = (const float*)d_in[1];   // [E,1,64]
    const int*   src    = (const int*)d_in[2];     // [E]
    const int*   dst    = (const int*)d_in[3];     // [E]
    const float* Wm     = (const float*)d_in[4];   // [64,128]
    const float* bm     = (const float*)d_in[5];   // [64]
    const float* Wa     = (const float*)d_in[6];   // [64,128]
    const float* ba     = (const float*)d_in[7];   // [64]
    float* out = (float*)d_out;                    // [N,1,64] fp32

    const int N = in_sizes[0] / 64;
    const int E = in_sizes[2];
    const int NB = (N + 255) / 256;                // scan blocks (196 <= 256)

    // workspace layout:
    float* agg      = (float*)d_ws;                // N*128 f32
    float* deg      = agg + (size_t)N * 128;       // N f32
    float* WmT      = deg + N;                     // 8192 f32
    float* WaT      = WmT + 8192;                  // 8192 f32
    int*   cnt      = (int*)(WaT + 8192);          // N i32
    int*   offs     = cnt + N;                     // N+1 i32
    int*   cursor   = offs + N + 1;                // N i32
    int*   bsums    = cursor + N;                  // 256 i32
    int*   eids     = bsums + 256;                 // E i32
    int*   src_perm = eids + E;                    // E i32

    (void)hipMemsetAsync(cnt, 0, (size_t)N * sizeof(int), stream);

    transpose_w<<<64, 256, 0, stream>>>(Wm, Wa, WmT, WaT);
    histogram<<<(E + 255) / 256, 256, 0, stream>>>(dst, cnt, E);
    scan_local<<<NB, 256, 0, stream>>>(cnt, offs, bsums, N);
    scan_bsums<<<1, 256, 0, stream>>>(bsums, NB);
    scan_add<<<NB, 256, 0, stream>>>(offs, cursor, bsums, N, E);
    scatter_eids<<<(E + 255) / 256, 256, 0, stream>>>(dst, src, cursor, eids, src_perm, E);
    gather_csr<<<(N + 3) / 4, 256, 0, stream>>>(
        (const float4*)nfeats, (const float4*)efeats, src_perm, offs, eids,
        (float4*)agg, deg, N);
    node_update<<<(N + 3) / 4, 64, 0, stream>>>(nfeats, agg, deg, WmT, bm, WaT, ba, out, N);
}